// Round 18
// baseline (135.827 us; speedup 1.0000x reference)
//
#include <hip/hip_runtime.h>
#include <hip/hip_fp16.h>
#include <stdint.h>

// x[16384,2048] f32, w[2048,2048] f32, bias[2048] f32, scalar scales.
// M=16384, N=2048, K=2048. Output f16 values stored as f32.
#define MDIM 16384
#define NDIM 2048
#define KDIM 2048

typedef __attribute__((ext_vector_type(4))) float f32x4;
typedef __attribute__((ext_vector_type(4))) int   i32x4;
typedef __attribute__((ext_vector_type(8))) int   i32x8;

#if defined(__has_builtin)
#if __has_builtin(__builtin_amdgcn_cvt_pk_fp8_f32)
#define HAVE_CVT_PK_FP8 1
#endif
#endif

// ---------------------------------------------------------------------------
// f32 -> e4m3fn (OCP), RTNE, saturating (== clip(+-448) then cast).
// ---------------------------------------------------------------------------
__device__ __forceinline__ unsigned f32_to_e4m3(float x) {
    float q = fminf(448.f, fmaxf(-448.f, x));
    unsigned ub = __float_as_uint(q);
    unsigned sgn = (ub >> 24) & 0x80u;
    float aq = fabsf(q);
    int E = (int)((__float_as_uint(aq) >> 23) & 0xff) - 127;
    if (E < -6) E = -6;
    float rq = __uint_as_float((unsigned)(130 - E) << 23);  // 2^(3-E), exact
    int m = (int)rintf(aq * rq);                            // RTNE, exact scale
    if (m == 16) { m = 8; E += 1; }
    unsigned bits;
    if (m < 8) bits = sgn | (unsigned)m;
    else       bits = sgn | ((unsigned)(E + 7) << 3) | (unsigned)(m - 8);
    return bits;
}

__device__ __forceinline__ uint32_t pack4_e4m3(float a, float b, float c, float d) {
#ifdef HAVE_CVT_PK_FP8
    int r = __builtin_amdgcn_cvt_pk_fp8_f32(a, b, 0, false);   // bytes 0-1
    r = __builtin_amdgcn_cvt_pk_fp8_f32(c, d, r, true);        // bytes 2-3
    return (uint32_t)r;
#else
    return f32_to_e4m3(a) | (f32_to_e4m3(b) << 8) |
           (f32_to_e4m3(c) << 16) | (f32_to_e4m3(d) << 24);
#endif
}

// x-quant: linear layout.  w-quant: fragment-major packed layout Bp
// (verified r8-r17): 2048B block (n16 = col>>4, kb = ktile) holds at
// lane*32 (lane = g*16 + r15) bytes w[n16*16+r15][kb*128 + g*32 .. +31].
__global__ void quant_both_kernel(const float* __restrict__ x,
                                  uint8_t* __restrict__ xq,
                                  const float* __restrict__ w,
                                  uint8_t* __restrict__ wq,
                                  const float* __restrict__ s_in,
                                  const float* __restrict__ s_w) {
    if (blockIdx.x < 2048) {
        float sc = s_in[0];
        unsigned n16 = (unsigned)((size_t)MDIM * KDIM / 16);
        unsigned i = blockIdx.x * 256 + threadIdx.x;
        for (; i < n16; i += 2048 * 256) {
            const float4* xp = (const float4*)(x + (size_t)i * 16);
            uint32_t wd[4];
#pragma unroll
            for (int j = 0; j < 4; ++j) {
                float4 v = xp[j];
                wd[j] = pack4_e4m3(v.x / sc, v.y / sc, v.z / sc, v.w / sc);
            }
            ((uint4*)xq)[i] = make_uint4(wd[0], wd[1], wd[2], wd[3]);
        }
    } else {
        float sc = s_w[0];
        unsigned n16 = (unsigned)((size_t)NDIM * KDIM / 16);
        unsigned i = (blockIdx.x - 2048) * 256 + threadIdx.x;
        for (; i < n16; i += 256 * 256) {
            const float4* xp = (const float4*)(w + (size_t)i * 16);
            uint32_t wd[4];
#pragma unroll
            for (int j = 0; j < 4; ++j) {
                float4 v = xp[j];
                wd[j] = pack4_e4m3(v.x / sc, v.y / sc, v.z / sc, v.w / sc);
            }
            unsigned r = i >> 7, kc = i & 127;
            unsigned idx = ((r >> 4) * 16 + (kc >> 3)) * 128 +
                           ((kc & 7) >> 1) * 32 + (r & 15) * 2 + (kc & 1);
            ((uint4*)wq)[idx] = make_uint4(wd[0], wd[1], wd[2], wd[3]);
        }
    }
}

// ---------------------------------------------------------------------------
// GEMM: C = Aq * Bp^T, fp8 e4m3, mfma_scale_f32_16x16x128_f8f6f4 (unit
// scales: exact, 2x fp8 rate; verified r4-r17).
//
// Round-18: ZERO-BARRIER K-LOOP, wave-private pipelines.  r13-r17 (five
// structures) all pinned at 76+-1us; the last common trait is block-wide
// barrier lockstep (a wave's private stall convoys all 8 waves; the 2
// co-resident blocks' waves enter MFMA phases together instead of
// phase-offsetting).  Here each wave:
//   - stages its OWN 64-row A-slice into a PRIVATE LDS dbuf (2 x 8KiB;
//     wc-pair duplication accepted: LDS ~128KB/CU-tile ~1400cy, ok)
//   - reads only what it staged (no cross-wave LDS sharing in the K-loop)
//   - paces itself with per-wave vmcnt only; NO s_barrier until epilogue.
// Per-wave FIFO invariant entering tile t: [bf(t) 16 oldest][A(t+1) 8];
// MFMAs retire bf progressively (n-outer); LOAD_BF_ALL(t+1) 16;
// vmcnt(16) retires A(t+1); STAGE_W(t+2) 8 restores invariant.
// Private staging algebra: chunk p = i*64+lane; local row = p>>3; swizzle
// c = ((lane&7)-((lane>>3)&7))&7 (per-lane const); src collapses to
// sbase + i*8*KDIM + kt*128; dst = dbase + h*8192 + i*1024 (+lane*16 HW).
// Read-side perm ((2g + r15)&7)<<4 unchanged (local row &7 == r15&7).
//
// Geometry (r14/r17): block 128x256, 4 waves 2Mx2N, per-wave 64x128,
// bf direct from packed wq (L2), 2 blocks/CU (launch_bounds(256,2)),
// LDS 64KiB/block (4 waves x 16KiB private dbuf).
// Epilogue: one __syncthreads, then [32][256] f32 slab, 4 passes (r14).
// ---------------------------------------------------------------------------
#define BM 128
#define BN 256
#define BKB 128
#define NKT (KDIM / BKB)   // 16

__device__ __forceinline__ void gload_lds16(const uint8_t* g, uint8_t* l) {
    __builtin_amdgcn_global_load_lds(
        (const __attribute__((address_space(1))) void*)g,
        (__attribute__((address_space(3))) void*)l, 16, 0, 0);
}

__device__ __forceinline__ void barrier_raw() {
    asm volatile("" ::: "memory");
    __builtin_amdgcn_s_barrier();
    asm volatile("" ::: "memory");
}

__global__ __launch_bounds__(256, 2) void gemm_fp8_kernel(
    const uint8_t* __restrict__ Aq, const uint8_t* __restrict__ Bp,
    const float* __restrict__ bias, const float* __restrict__ s_in,
    const float* __restrict__ s_w, float* __restrict__ out) {

    extern __shared__ uint8_t lds[];   // 65536 B: 4 waves x (2 x 8KiB) / slab

    // XCD-aware bijective swizzle (nwg = 1024, divisible by 8)
    int nwg = gridDim.x;
    int cpx = nwg >> 3;
    int bid = blockIdx.x;
    int swz = (bid & 7) * cpx + (bid >> 3);
    int tm = swz >> 3;                 // tiles_n = 8
    int tn = swz & 7;
    int row0 = tm * BM;
    int col0 = tn * BN;

    int tid  = threadIdx.x;
    int lane = tid & 63;
    int wid  = tid >> 6;               // 4 waves
    int wr = wid >> 1, wc = wid & 1;   // 2M x 2N, per-wave 64x128
    int r15 = lane & 15;
    int g   = lane >> 4;

    int perm0 = ((2 * g + r15) & 7) << 4;
    int perm1 = ((2 * g + 1 + r15) & 7) << 4;

    // ---- wave-private A staging ----
    // chunk p = i*64+lane; local row = i*8 + (lane>>3); phys c = lane&7;
    // logical c = ((lane&7) - ((lane>>3)&7)) & 7  (per-lane constant).
    int csw = ((lane & 7) - ((lane >> 3) & 7)) & 7;
    const uint8_t* sbase = Aq + (size_t)(row0 + wr * 64 + (lane >> 3)) * KDIM
                              + csw * 16;
    uint8_t* dbase = lds + wid * 16384 + lane * 16;

#define STAGE_W(KT, H)                                                        \
    {                                                                         \
        _Pragma("unroll")                                                     \
        for (int i_ = 0; i_ < 8; ++i_)                                        \
            gload_lds16(sbase + (size_t)(KT) * BKB + (size_t)i_ * (8 * KDIM), \
                        dbase + (H) * 8192 + i_ * 1024);                      \
    }

    // ---- B fragment base (packed layout; r8-r17-verified) ----
    const uint8_t* Bbase = Bp + (size_t)(tn * 16 + wc * 8) * 32768 + lane * 32;

#define LOAD_BF1(DST, N, KT)                                                  \
    {                                                                         \
        const uint8_t* p_ = Bbase + (size_t)(N) * 32768 + (size_t)(KT) * 2048; \
        i32x4 lo = *(const i32x4*)p_;                                         \
        i32x4 hi = *(const i32x4*)(p_ + 16);                                  \
        _Pragma("unroll")                                                     \
        for (int q_ = 0; q_ < 4; ++q_) { DST[q_] = lo[q_]; DST[4 + q_] = hi[q_]; } \
    }

#define LOAD_BF_ALL(KT)                                                       \
    LOAD_BF1(bf0, 0, KT); LOAD_BF1(bf1, 1, KT);                               \
    LOAD_BF1(bf2, 2, KT); LOAD_BF1(bf3, 3, KT);                               \
    LOAD_BF1(bf4, 4, KT); LOAD_BF1(bf5, 5, KT);                               \
    LOAD_BF1(bf6, 6, KT); LOAD_BF1(bf7, 7, KT);

    // af read from private buf: local row = m*16 + r15
#define LOAD_AF1(DST, H, M)                                                   \
    {                                                                         \
        const uint8_t* rp = lds + wid * 16384 + (H) * 8192 +                  \
                            ((M) * 16 + r15) * 128;                           \
        i32x4 lo = *(const i32x4*)(rp + perm0);                               \
        i32x4 hi = *(const i32x4*)(rp + perm1);                               \
        _Pragma("unroll")                                                     \
        for (int q_ = 0; q_ < 4; ++q_) { DST[q_] = lo[q_]; DST[4 + q_] = hi[q_]; } \
    }

    // n-outer burst: 4 MFMAs (af0..af3) against one bf fragment
#define MFMA4N(BF, N)                                                         \
    __builtin_amdgcn_s_setprio(1);                                            \
    acc[0][N] = __builtin_amdgcn_mfma_scale_f32_16x16x128_f8f6f4(             \
        af0, BF, acc[0][N], 0, 0, 0, 127, 0, 127);                            \
    acc[1][N] = __builtin_amdgcn_mfma_scale_f32_16x16x128_f8f6f4(             \
        af1, BF, acc[1][N], 0, 0, 0, 127, 0, 127);                            \
    acc[2][N] = __builtin_amdgcn_mfma_scale_f32_16x16x128_f8f6f4(             \
        af2, BF, acc[2][N], 0, 0, 0, 127, 0, 127);                            \
    acc[3][N] = __builtin_amdgcn_mfma_scale_f32_16x16x128_f8f6f4(             \
        af3, BF, acc[3][N], 0, 0, 0, 127, 0, 127);                            \
    __builtin_amdgcn_s_setprio(0);

    f32x4 acc[4][8];
#pragma unroll
    for (int m = 0; m < 4; ++m)
#pragma unroll
        for (int n = 0; n < 8; ++n)
            acc[m][n] = (f32x4){0.f, 0.f, 0.f, 0.f};

    i32x8 bf0, bf1, bf2, bf3, bf4, bf5, bf6, bf7;
    i32x8 af0, af1, af2, af3;

    // ---- per-wave prologue (no barrier): A(0); bf(0); A(1);
    //      vmcnt(24) retires A(0)'s 8 DMA only ----
    STAGE_W(0, 0);
    asm volatile("" ::: "memory");
    LOAD_BF_ALL(0);
    asm volatile("" ::: "memory");
    STAGE_W(1, 1);
    asm volatile("s_waitcnt vmcnt(24)" ::: "memory");

    // Per-wave invariant entering tile T: A(T) landed in private buf T&1;
    // outstanding = [bf(T) 16 oldest][A(T+1) 8].
    for (int t = 0; t < NKT; ++t) {
        const int h = t & 1;
        LOAD_AF1(af0, h, 0); LOAD_AF1(af1, h, 1);
        LOAD_AF1(af2, h, 2); LOAD_AF1(af3, h, 3);
        MFMA4N(bf0, 0);      // compiler: progressive counted vmcnt per bf
        MFMA4N(bf1, 1);
        MFMA4N(bf2, 2);
        MFMA4N(bf3, 3);
        MFMA4N(bf4, 4);
        MFMA4N(bf5, 5);
        MFMA4N(bf6, 6);
        MFMA4N(bf7, 7);
        if (t + 1 < NKT) {
            asm volatile("" ::: "memory");
            LOAD_BF_ALL(t + 1);                        // 16 loads, regs free
            asm volatile("s_waitcnt vmcnt(16)" ::: "memory");  // A(t+1) in
            if (t + 2 < NKT) {
                asm volatile("" ::: "memory");
                STAGE_W(t + 2, h);                     // 8 DMA, youngest
            }
        }
    }
    asm volatile("s_waitcnt vmcnt(0)" ::: "memory");

    // ---- epilogue: single sync, then f16 double-round + bias via
    //      [32][256] f32 slab (overlays the now-dead private bufs) ----
    __syncthreads();

    float s = s_in[0] * s_w[0];
    float* slab = (float*)lds;
    __half hb[8];
#pragma unroll
    for (int n = 0; n < 8; ++n)
        hb[n] = __float2half(bias[col0 + wc * 128 + n * 16 + r15]);

#pragma unroll
    for (int q = 0; q < 4; ++q) {            // out rows [q*32, q*32+32)
        if (wr == (q >> 1)) {
            const int mbase = 2 * (q & 1);
#pragma unroll
            for (int n = 0; n < 8; ++n) {
                int colb = wc * 128 + n * 16 + r15;
#pragma unroll
                for (int mm = 0; mm < 2; ++mm) {
                    int sr = mm * 16 + g * 4;
#pragma unroll
                    for (int r = 0; r < 4; ++r) {
                        __half h = __float2half(acc[mbase + mm][n][r] * s);
                        slab[(sr + r) * 256 + colb] = __half2float(__hadd(h, hb[n]));
                    }
                }
            }
        }
        barrier_raw();
        // 32 rows x 1KiB; each wave 8 rows (64 lanes x 16B per row)
#pragma unroll
        for (int it = 0; it < 8; ++it) {
            int srow = wid * 8 + it;
            f32x4 vv = *(const f32x4*)&slab[srow * 256 + lane * 4];
            int grow = row0 + q * 32 + srow;
            *(f32x4*)&out[(size_t)grow * NDIM + col0 + lane * 4] = vv;
        }
        barrier_raw();
    }
#undef STAGE_W
#undef LOAD_BF1
#undef LOAD_BF_ALL
#undef LOAD_AF1
#undef MFMA4N
}

// ---------------------------------------------------------------------------
extern "C" void kernel_launch(void* const* d_in, const int* in_sizes, int n_in,
                              void* d_out, int out_size, void* d_ws, size_t ws_size,
                              hipStream_t stream) {
    const float* x      = (const float*)d_in[0];   // [16384, 2048]
    const float* weight = (const float*)d_in[1];   // [2048, 2048]
    const float* bias   = (const float*)d_in[2];   // [2048]
    const float* s_in   = (const float*)d_in[3];   // [1]
    const float* s_w    = (const float*)d_in[4];   // [1]
    float* out          = (float*)d_out;

    uint8_t* xq = (uint8_t*)d_ws;                          // 33.5 MB (linear)
    uint8_t* wq = (uint8_t*)d_ws + (size_t)MDIM * KDIM;    // 4.2 MB (packed)

    quant_both_kernel<<<2304, 256, 0, stream>>>(x, xq, weight, wq, s_in, s_w);

    dim3 grid((MDIM / BM) * (NDIM / BN));   // 128 * 8 = 1024
    gemm_fp8_kernel<<<grid, 256, 65536, stream>>>(xq, wq, bias, s_in, s_w, out);
}

// Round 20
// 111.497 us; speedup vs baseline: 1.2182x; 1.2182x over previous
//
#include <hip/hip_runtime.h>
#include <hip/hip_fp16.h>
#include <stdint.h>

// x[16384,2048] f32, w[2048,2048] f32, bias[2048] f32, scalar scales.
// M=16384, N=2048, K=2048. Output f16 values stored as f32.
//
// FINAL (r20 = r17 verbatim, best verified: 111.48us total, GEMM 76.1us
// = 1807 TF, absmax 0.031).  r19's 3-wave/SIMD H2 probe failed correctness:
// launch_bounds(256,3) register cap -> spill -> scratch ops increment vmcnt
// -> hand-counted waits invalidated (lesson: counted vmcnt requires a
// provably spill-free kernel).  H2 itself is structurally untestable:
// 3 waves/SIMD caps acc at 64 -> 64x64 wave tiles -> ~144KB operand
// traffic per CU-tile vs ~830cy MFMA -> L2-bound; occupancy and intensity
// trade off through the register file, so 2 waves/SIMD at ~240 regs is
// the feasible optimum.  Plateau evidence: six distinct structures
// (r12-r18) all 76+-1us, MfmaUtil x wall == 29.5us MFMA floor.
#define MDIM 16384
#define NDIM 2048
#define KDIM 2048

typedef __attribute__((ext_vector_type(4))) float f32x4;
typedef __attribute__((ext_vector_type(4))) int   i32x4;
typedef __attribute__((ext_vector_type(8))) int   i32x8;

#if defined(__has_builtin)
#if __has_builtin(__builtin_amdgcn_cvt_pk_fp8_f32)
#define HAVE_CVT_PK_FP8 1
#endif
#endif

// ---------------------------------------------------------------------------
// f32 -> e4m3fn (OCP), RTNE, saturating (== clip(+-448) then cast).
// ---------------------------------------------------------------------------
__device__ __forceinline__ unsigned f32_to_e4m3(float x) {
    float q = fminf(448.f, fmaxf(-448.f, x));
    unsigned ub = __float_as_uint(q);
    unsigned sgn = (ub >> 24) & 0x80u;
    float aq = fabsf(q);
    int E = (int)((__float_as_uint(aq) >> 23) & 0xff) - 127;
    if (E < -6) E = -6;
    float rq = __uint_as_float((unsigned)(130 - E) << 23);  // 2^(3-E), exact
    int m = (int)rintf(aq * rq);                            // RTNE, exact scale
    if (m == 16) { m = 8; E += 1; }
    unsigned bits;
    if (m < 8) bits = sgn | (unsigned)m;
    else       bits = sgn | ((unsigned)(E + 7) << 3) | (unsigned)(m - 8);
    return bits;
}

__device__ __forceinline__ uint32_t pack4_e4m3(float a, float b, float c, float d) {
#ifdef HAVE_CVT_PK_FP8
    int r = __builtin_amdgcn_cvt_pk_fp8_f32(a, b, 0, false);   // bytes 0-1
    r = __builtin_amdgcn_cvt_pk_fp8_f32(c, d, r, true);        // bytes 2-3
    return (uint32_t)r;
#else
    return f32_to_e4m3(a) | (f32_to_e4m3(b) << 8) |
           (f32_to_e4m3(c) << 16) | (f32_to_e4m3(d) << 24);
#endif
}

// x-quant: linear layout.  w-quant: fragment-major packed layout Bp
// (verified r8-r17): 2048B block (n16 = col>>4, kb = ktile) holds at
// lane*32 (lane = g*16 + r15) bytes w[n16*16+r15][kb*128 + g*32 .. +31].
__global__ void quant_both_kernel(const float* __restrict__ x,
                                  uint8_t* __restrict__ xq,
                                  const float* __restrict__ w,
                                  uint8_t* __restrict__ wq,
                                  const float* __restrict__ s_in,
                                  const float* __restrict__ s_w) {
    if (blockIdx.x < 2048) {
        float sc = s_in[0];
        unsigned n16 = (unsigned)((size_t)MDIM * KDIM / 16);
        unsigned i = blockIdx.x * 256 + threadIdx.x;
        for (; i < n16; i += 2048 * 256) {
            const float4* xp = (const float4*)(x + (size_t)i * 16);
            uint32_t wd[4];
#pragma unroll
            for (int j = 0; j < 4; ++j) {
                float4 v = xp[j];
                wd[j] = pack4_e4m3(v.x / sc, v.y / sc, v.z / sc, v.w / sc);
            }
            ((uint4*)xq)[i] = make_uint4(wd[0], wd[1], wd[2], wd[3]);
        }
    } else {
        float sc = s_w[0];
        unsigned n16 = (unsigned)((size_t)NDIM * KDIM / 16);
        unsigned i = (blockIdx.x - 2048) * 256 + threadIdx.x;
        for (; i < n16; i += 256 * 256) {
            const float4* xp = (const float4*)(w + (size_t)i * 16);
            uint32_t wd[4];
#pragma unroll
            for (int j = 0; j < 4; ++j) {
                float4 v = xp[j];
                wd[j] = pack4_e4m3(v.x / sc, v.y / sc, v.z / sc, v.w / sc);
            }
            unsigned r = i >> 7, kc = i & 127;
            unsigned idx = ((r >> 4) * 16 + (kc >> 3)) * 128 +
                           ((kc & 7) >> 1) * 32 + (r & 15) * 2 + (kc & 1);
            ((uint4*)wq)[idx] = make_uint4(wd[0], wd[1], wd[2], wd[3]);
        }
    }
}

// ---------------------------------------------------------------------------
// GEMM: C = Aq * Bp^T, fp8 e4m3, mfma_scale_f32_16x16x128_f8f6f4 (unit
// scales: exact, 2x fp8 rate; verified r4-r17).
// Geometry: block 128x256, 4 waves 2Mx2N, per-wave 64x128, bf direct from
// packed wq (L2-resident), af via LDS dbuf 2x16KiB, 2 blocks/CU
// (launch_bounds(256,2)).  N-outer MFMA bursts give progressive per-bf
// counted waits; one barrier + one vmcnt(16) per tile.
// FIFO per tile t: entry [bf(t) 16]; STAGE_A(t+1) 4 -> 20; MFMA bursts
// retire bf progressively; LOAD_BF_ALL(t+1) -> (rest + 16); vmcnt(16)
// retires A(t+1); barrier.
// A chunk swizzle per 128B row: phys=(c+row)&7 (2-way residual, r4-r17).
// Epilogue: [32][256] f32 slab, 4 passes, 1KiB dwordx4 rows.
// ---------------------------------------------------------------------------
#define BM 128
#define BN 256
#define BKB 128
#define NKT (KDIM / BKB)   // 16

__device__ __forceinline__ void gload_lds16(const uint8_t* g, uint8_t* l) {
    __builtin_amdgcn_global_load_lds(
        (const __attribute__((address_space(1))) void*)g,
        (__attribute__((address_space(3))) void*)l, 16, 0, 0);
}

__device__ __forceinline__ void barrier_raw() {
    asm volatile("" ::: "memory");
    __builtin_amdgcn_s_barrier();
    asm volatile("" ::: "memory");
}

__global__ __launch_bounds__(256, 2) void gemm_fp8_kernel(
    const uint8_t* __restrict__ Aq, const uint8_t* __restrict__ Bp,
    const float* __restrict__ bias, const float* __restrict__ s_in,
    const float* __restrict__ s_w, float* __restrict__ out) {

    extern __shared__ uint8_t lds[];   // 32768 B: 2 x 16KiB A-dbuf / slab

    // XCD-aware bijective swizzle (nwg = 1024, divisible by 8)
    int nwg = gridDim.x;
    int cpx = nwg >> 3;
    int bid = blockIdx.x;
    int swz = (bid & 7) * cpx + (bid >> 3);
    int tm = swz >> 3;                 // tiles_n = 8
    int tn = swz & 7;
    int row0 = tm * BM;
    int col0 = tn * BN;

    int tid  = threadIdx.x;
    int lane = tid & 63;
    int wid  = tid >> 6;               // 4 waves
    int wr = wid >> 1, wc = wid & 1;   // 2M x 2N, per-wave 64x128
    int r15 = lane & 15;
    int g   = lane >> 4;

    int perm0 = ((2 * g + r15) & 7) << 4;
    int perm1 = ((2 * g + 1 + r15) & 7) << 4;

    // ---- A staging: 1024 chunks/tile (128 rows x 8), 4 per thread ----
    int ssrc[4], sdst[4];
#pragma unroll
    for (int i = 0; i < 4; ++i) {
        int p = i * 256 + tid;
        int lrow = p >> 3;
        int c = ((p & 7) - (lrow & 7)) & 7;
        ssrc[i] = lrow * KDIM + c * 16;
        sdst[i] = p * 16;
    }
    const uint8_t* Asrc = Aq + (size_t)row0 * KDIM;

#define STAGE_A(KT, BUF)                                                      \
    {                                                                         \
        _Pragma("unroll")                                                     \
        for (int j_ = 0; j_ < 4; ++j_)                                        \
            gload_lds16(Asrc + ssrc[j_] + (size_t)(KT) * BKB, (BUF) + sdst[j_]); \
    }

    // ---- B fragment base (packed layout; r8-r17-verified) ----
    const uint8_t* Bbase = Bp + (size_t)(tn * 16 + wc * 8) * 32768 + lane * 32;

#define LOAD_BF1(DST, N, KT)                                                  \
    {                                                                         \
        const uint8_t* p_ = Bbase + (size_t)(N) * 32768 + (size_t)(KT) * 2048; \
        i32x4 lo = *(const i32x4*)p_;                                         \
        i32x4 hi = *(const i32x4*)(p_ + 16);                                  \
        _Pragma("unroll")                                                     \
        for (int q_ = 0; q_ < 4; ++q_) { DST[q_] = lo[q_]; DST[4 + q_] = hi[q_]; } \
    }

    // issue order 0..7 => FIFO age order matches burst order (progressive waits)
#define LOAD_BF_ALL(KT)                                                       \
    LOAD_BF1(bf0, 0, KT); LOAD_BF1(bf1, 1, KT);                               \
    LOAD_BF1(bf2, 2, KT); LOAD_BF1(bf3, 3, KT);                               \
    LOAD_BF1(bf4, 4, KT); LOAD_BF1(bf5, 5, KT);                               \
    LOAD_BF1(bf6, 6, KT); LOAD_BF1(bf7, 7, KT);

    int aRow0 = wr * 64 + r15;         // + m*16

#define LOAD_AF1(DST, bo, M)                                                  \
    {                                                                         \
        const uint8_t* rp = lds + (bo) + (aRow0 + (M) * 16) * 128;            \
        i32x4 lo = *(const i32x4*)(rp + perm0);                               \
        i32x4 hi = *(const i32x4*)(rp + perm1);                               \
        _Pragma("unroll")                                                     \
        for (int q_ = 0; q_ < 4; ++q_) { DST[q_] = lo[q_]; DST[4 + q_] = hi[q_]; } \
    }

    // n-outer burst: 4 MFMAs (af0..af3) against one bf fragment
#define MFMA4N(BF, N)                                                         \
    __builtin_amdgcn_s_setprio(1);                                            \
    acc[0][N] = __builtin_amdgcn_mfma_scale_f32_16x16x128_f8f6f4(             \
        af0, BF, acc[0][N], 0, 0, 0, 127, 0, 127);                            \
    acc[1][N] = __builtin_amdgcn_mfma_scale_f32_16x16x128_f8f6f4(             \
        af1, BF, acc[1][N], 0, 0, 0, 127, 0, 127);                            \
    acc[2][N] = __builtin_amdgcn_mfma_scale_f32_16x16x128_f8f6f4(             \
        af2, BF, acc[2][N], 0, 0, 0, 127, 0, 127);                            \
    acc[3][N] = __builtin_amdgcn_mfma_scale_f32_16x16x128_f8f6f4(             \
        af3, BF, acc[3][N], 0, 0, 0, 127, 0, 127);                            \
    __builtin_amdgcn_s_setprio(0);

    f32x4 acc[4][8];
#pragma unroll
    for (int m = 0; m < 4; ++m)
#pragma unroll
        for (int n = 0; n < 8; ++n)
            acc[m][n] = (f32x4){0.f, 0.f, 0.f, 0.f};

    i32x8 bf0, bf1, bf2, bf3, bf4, bf5, bf6, bf7;
    i32x8 af0, af1, af2, af3;

    uint8_t* buf0 = &lds[0];
    uint8_t* buf1 = &lds[16384];

    // ---- prologue: stage A(0) [4 DMA]; bf(0) [16 loads];
    //      vmcnt(16) drains DMA, leaves bf(0) in flight; barrier ----
    STAGE_A(0, buf0);
    asm volatile("" ::: "memory");     // pin DMA before bf in VMEM FIFO
    LOAD_BF_ALL(0);
    asm volatile("s_waitcnt vmcnt(16)" ::: "memory");
    barrier_raw();

    // Entry invariant tile T: bf(T) 16 in flight (oldest), A(T) landed.
#define TILE_BODY(T)                                                          \
    {                                                                         \
        const unsigned bo = ((unsigned)(T) & 1) << 14;                        \
        uint8_t* nxt_ = (((T) & 1) ? buf0 : buf1);                            \
        if ((T) + 1 < NKT) STAGE_A((T) + 1, nxt_);   /* 4 DMA after bf(T) */  \
        asm volatile("" ::: "memory");                                        \
        LOAD_AF1(af0, bo, 0); LOAD_AF1(af1, bo, 1);                           \
        LOAD_AF1(af2, bo, 2); LOAD_AF1(af3, bo, 3);                           \
        MFMA4N(bf0, 0);      /* compiler: vmcnt(18) - only bf0 needed */      \
        MFMA4N(bf1, 1);      /* vmcnt(16) */                                  \
        MFMA4N(bf2, 2);      /* vmcnt(14) ... progressive */                  \
        MFMA4N(bf3, 3);                                                       \
        MFMA4N(bf4, 4);                                                       \
        MFMA4N(bf5, 5);                                                       \
        MFMA4N(bf6, 6);                                                       \
        MFMA4N(bf7, 7);      /* vmcnt(4) at ~1270cy distance */               \
        if ((T) + 1 < NKT) {                                                  \
            asm volatile("" ::: "memory");                                    \
            LOAD_BF_ALL((T) + 1);          /* 16 loads, regs now free */      \
            asm volatile("s_waitcnt vmcnt(16)" ::: "memory"); /* A(T+1) in */ \
        } else {                                                              \
            asm volatile("s_waitcnt vmcnt(0)" ::: "memory");                  \
        }                                                                     \
        barrier_raw();                                                        \
    }

    for (int t = 0; t < NKT; ++t)
        TILE_BODY(t);

    // ---- epilogue: f16 double-round + bias; [32][256] f32 slab, 4 passes --
    float s = s_in[0] * s_w[0];
    float* slab = (float*)lds;
    __half hb[8];
#pragma unroll
    for (int n = 0; n < 8; ++n)
        hb[n] = __float2half(bias[col0 + wc * 128 + n * 16 + r15]);

#pragma unroll
    for (int q = 0; q < 4; ++q) {            // out rows [q*32, q*32+32)
        if (wr == (q >> 1)) {
            const int mbase = 2 * (q & 1);
#pragma unroll
            for (int n = 0; n < 8; ++n) {
                int colb = wc * 128 + n * 16 + r15;
#pragma unroll
                for (int mm = 0; mm < 2; ++mm) {
                    int sr = mm * 16 + g * 4;
#pragma unroll
                    for (int r = 0; r < 4; ++r) {
                        __half h = __float2half(acc[mbase + mm][n][r] * s);
                        slab[(sr + r) * 256 + colb] = __half2float(__hadd(h, hb[n]));
                    }
                }
            }
        }
        barrier_raw();
        // 32 rows x 1KiB; each wave 8 rows (64 lanes x 16B per row)
#pragma unroll
        for (int it = 0; it < 8; ++it) {
            int srow = wid * 8 + it;
            f32x4 vv = *(const f32x4*)&slab[srow * 256 + lane * 4];
            int grow = row0 + q * 32 + srow;
            *(f32x4*)&out[(size_t)grow * NDIM + col0 + lane * 4] = vv;
        }
        barrier_raw();
    }
#undef STAGE_A
#undef LOAD_BF1
#undef LOAD_BF_ALL
#undef LOAD_AF1
#undef MFMA4N
#undef TILE_BODY
}

// ---------------------------------------------------------------------------
extern "C" void kernel_launch(void* const* d_in, const int* in_sizes, int n_in,
                              void* d_out, int out_size, void* d_ws, size_t ws_size,
                              hipStream_t stream) {
    const float* x      = (const float*)d_in[0];   // [16384, 2048]
    const float* weight = (const float*)d_in[1];   // [2048, 2048]
    const float* bias   = (const float*)d_in[2];   // [2048]
    const float* s_in   = (const float*)d_in[3];   // [1]
    const float* s_w    = (const float*)d_in[4];   // [1]
    float* out          = (float*)d_out;

    uint8_t* xq = (uint8_t*)d_ws;                          // 33.5 MB (linear)
    uint8_t* wq = (uint8_t*)d_ws + (size_t)MDIM * KDIM;    // 4.2 MB (packed)

    quant_both_kernel<<<2304, 256, 0, stream>>>(x, xq, weight, wq, s_in, s_w);

    dim3 grid((MDIM / BM) * (NDIM / BN));   // 128 * 8 = 1024
    gemm_fp8_kernel<<<grid, 256, 32768, stream>>>(xq, wq, bias, s_in, s_w, out);
}